// Round 13
// baseline (448.593 us; speedup 1.0000x reference)
//
#include <hip/hip_runtime.h>
#include <math.h>

#define D 128
#define NTT 64   // nodes per block (transform/gate), 16 per wave
#define LP 132   // padded f32 LDS row
#define SCB 64   // scan blocks
#define HB 512   // histogram blocks fused into transform launch

__device__ __forceinline__ float wave_allsum(float v) {
    #pragma unroll
    for (int off = 32; off; off >>= 1) v += __shfl_xor(v, off);
    return v;
}

// ======================= fused: histogram (blocks 0..HB-1) + transform =======
// transform: h=relu(LN(x@W1+b1)); A=h@We1_top+be1; B=h@We1_bot
// 64 nodes/block, 256 threads, barrier-free; wave q owns nodes q*16..q*16+15.
// AH[node][0:128]=A, AH[node][128:256]=h
__global__ void __launch_bounds__(256) fused_hist_transform(
    const int* __restrict__ ei, int* __restrict__ deg, int E,
    const float* __restrict__ x, const float* __restrict__ W1, const float* __restrict__ b1,
    const float* __restrict__ g1, const float* __restrict__ bt1,
    const float* __restrict__ We1, const float* __restrict__ be1,
    float* __restrict__ AH, float* __restrict__ B, int N)
{
    if (blockIdx.x < HB) {
        for (int e = blockIdx.x * 256 + threadIdx.x; e < E; e += HB * 256)
            atomicAdd(&deg[ei[E + e]], 1);
        return;
    }
    __shared__ float xs[NTT][LP];   // x, then h in place (wave-local)
    const int t = threadIdx.x;
    const int q = t >> 6, lane = t & 63;
    const int c = lane;
    const int base = (blockIdx.x - HB) * NTT;

    // stage x: thread t -> node t>>2, 32 cols at (t&3)*32 (wave-local rows)
    {
        int node = t >> 2, c0 = (t & 3) * 32;
        int gn = min(base + node, N - 1);
        const float4* src = (const float4*)(x + (size_t)gn * D + c0);
        float4* dst = (float4*)&xs[node][c0];
        #pragma unroll
        for (int i = 0; i < 8; ++i) dst[i] = src[i];
    }

    // GEMM1: y = x@W1
    float acc[16][2];
    #pragma unroll
    for (int n = 0; n < 16; ++n) { acc[n][0] = 0.f; acc[n][1] = 0.f; }
    for (int k = 0; k < 128; k += 4) {
        float w00 = W1[(k+0)*128 + c], w01 = W1[(k+0)*128 + c + 64];
        float w10 = W1[(k+1)*128 + c], w11 = W1[(k+1)*128 + c + 64];
        float w20 = W1[(k+2)*128 + c], w21 = W1[(k+2)*128 + c + 64];
        float w30 = W1[(k+3)*128 + c], w31 = W1[(k+3)*128 + c + 64];
        #pragma unroll
        for (int n = 0; n < 16; ++n) {
            float4 xv = *(const float4*)&xs[q*16+n][k];
            acc[n][0] += xv.x*w00 + xv.y*w10 + xv.z*w20 + xv.w*w30;
            acc[n][1] += xv.x*w01 + xv.y*w11 + xv.z*w21 + xv.w*w31;
        }
    }

    // LN + relu in registers; h -> xs (in place) + AH[.,128:256]
    {
        float b0 = b1[c], b1v = b1[c + 64];
        float gg0 = g1[c], gg1 = g1[c + 64];
        float bb0 = bt1[c], bb1 = bt1[c + 64];
        #pragma unroll
        for (int n = 0; n < 16; ++n) {
            int node = q * 16 + n;
            float v0 = acc[n][0] + b0, v1 = acc[n][1] + b1v;
            float s = wave_allsum(v0 + v1);
            float qq = wave_allsum(v0*v0 + v1*v1);
            float m = s * (1.f/128.f);
            float var = qq * (1.f/128.f) - m*m;
            float rs = rsqrtf(var + 1e-5f);
            float h0 = fmaxf((v0 - m)*rs*gg0 + bb0, 0.f);
            float h1 = fmaxf((v1 - m)*rs*gg1 + bb1, 0.f);
            xs[node][c]      = h0;
            xs[node][c + 64] = h1;
            int gn = base + node;
            if (gn < N) {
                AH[(size_t)gn * 256 + 128 + c]      = h0;
                AH[(size_t)gn * 256 + 128 + c + 64] = h1;
            }
        }
    }

    // GEMM2: A = h@We1[0:128,:] + be1 ; B = h@We1[128:256,:]
    float aA[16][2], aB[16][2];
    #pragma unroll
    for (int n = 0; n < 16; ++n) { aA[n][0]=0.f; aA[n][1]=0.f; aB[n][0]=0.f; aB[n][1]=0.f; }
    for (int k = 0; k < 128; k += 4) {
        float t00 = We1[(k+0)*128 + c],   t01 = We1[(k+0)*128 + c + 64];
        float t10 = We1[(k+1)*128 + c],   t11 = We1[(k+1)*128 + c + 64];
        float t20 = We1[(k+2)*128 + c],   t21 = We1[(k+2)*128 + c + 64];
        float t30 = We1[(k+3)*128 + c],   t31 = We1[(k+3)*128 + c + 64];
        float u00 = We1[(k+128)*128 + c], u01 = We1[(k+128)*128 + c + 64];
        float u10 = We1[(k+129)*128 + c], u11 = We1[(k+129)*128 + c + 64];
        float u20 = We1[(k+130)*128 + c], u21 = We1[(k+130)*128 + c + 64];
        float u30 = We1[(k+131)*128 + c], u31 = We1[(k+131)*128 + c + 64];
        #pragma unroll
        for (int n = 0; n < 16; ++n) {
            float4 hv = *(const float4*)&xs[q*16+n][k];
            aA[n][0] += hv.x*t00 + hv.y*t10 + hv.z*t20 + hv.w*t30;
            aA[n][1] += hv.x*t01 + hv.y*t11 + hv.z*t21 + hv.w*t31;
            aB[n][0] += hv.x*u00 + hv.y*u10 + hv.z*u20 + hv.w*u30;
            aB[n][1] += hv.x*u01 + hv.y*u11 + hv.z*u21 + hv.w*u31;
        }
    }
    {
        float be0 = be1[c], be1v = be1[c + 64];
        #pragma unroll
        for (int n = 0; n < 16; ++n) {
            int gn = base + q*16 + n;
            if (gn < N) {
                AH[(size_t)gn * 256 + c]      = aA[n][0] + be0;
                AH[(size_t)gn * 256 + c + 64] = aA[n][1] + be1v;
                B[(size_t)gn * D + c]         = aB[n][0];
                B[(size_t)gn * D + c + 64]    = aB[n][1];
            }
        }
    }
}

// ---- CSR build ----
__global__ void __launch_bounds__(256) scan_a(const int* __restrict__ deg,
                                              int* __restrict__ bsum, int N) {
    __shared__ int red[256];
    const int b = blockIdx.x, t = threadIdx.x;
    const int C = (N + SCB - 1) / SCB;
    const int W = (C + 255) / 256;
    int s0 = b * C + t * W;
    int s1 = min(s0 + W, min((b + 1) * C, N));
    int s = 0;
    for (int i = s0; i < s1; ++i) s += deg[i];
    red[t] = s;
    __syncthreads();
    #pragma unroll
    for (int d = 128; d; d >>= 1) {
        if (t < d) red[t] += red[t + d];
        __syncthreads();
    }
    if (t == 0) bsum[b] = red[0];
}

__global__ void __launch_bounds__(256) scan_c(const int* __restrict__ deg,
                                              const int* __restrict__ bsum,
                                              int* __restrict__ off,
                                              int* __restrict__ cursor, int N) {
    __shared__ int pre[256];
    __shared__ int bofs;
    const int b = blockIdx.x, t = threadIdx.x;
    const int C = (N + SCB - 1) / SCB;
    const int W = (C + 255) / 256;
    if (t == 0) {
        int r = 0;
        for (int i = 0; i < b; ++i) r += bsum[i];
        bofs = r;
        if (b == SCB - 1) off[N] = r + bsum[b];
    }
    int s0 = b * C + t * W;
    int s1 = min(s0 + W, min((b + 1) * C, N));
    int s = 0;
    for (int i = s0; i < s1; ++i) s += deg[i];
    pre[t] = s;
    __syncthreads();
    for (int d = 1; d < 256; d <<= 1) {
        int vv = (t >= d) ? pre[t - d] : 0;
        __syncthreads();
        if (t >= d) pre[t] += vv;
        __syncthreads();
    }
    int run = bofs + ((t == 0) ? 0 : pre[t - 1]);
    for (int i = s0; i < s1; ++i) {
        off[i] = run;
        cursor[i] = run;
        run += deg[i];
    }
}

__global__ void __launch_bounds__(256) scatter_kernel(const int* __restrict__ ei,
                                                      int* __restrict__ cursor,
                                                      int* __restrict__ ssrc, int E) {
    int e = blockIdx.x * 256 + threadIdx.x;
    if (e < E) {
        int pos = atomicAdd(&cursor[ei[E + e]], 1);
        ssrc[pos] = ei[e];
    }
}

// ======================= pull aggregation: wave/node, 16 lanes/edge, 8 edges in flight
__global__ void __launch_bounds__(256) agg_v6(
    const int* __restrict__ off, const int* __restrict__ ssrc,
    const float* __restrict__ AH, const float* __restrict__ B,
    const float* __restrict__ We2, const float* __restrict__ be2,
    float* __restrict__ aggr, int N)
{
    const int wid = threadIdx.x >> 6, lane = threadIdx.x & 63;
    const int node = blockIdx.x * 4 + wid;
    if (node >= N) return;
    const int g = lane >> 4;
    const int c8 = (lane & 15) * 8;

    const float4* Bp = (const float4*)(B + (size_t)node * D + c8);
    float4 b0 = Bp[0], b1 = Bp[1];
    const float4* Wp = (const float4*)(We2 + c8);
    float4 w0 = Wp[0], w1 = Wp[1];
    const float be = be2[0];

    float4 acc0 = make_float4(0.f,0.f,0.f,0.f);
    float4 acc1 = make_float4(0.f,0.f,0.f,0.f);

    const int s = off[node], e = off[node + 1];
    const int nit = (e - s + 7) >> 3;
    for (int it = 0; it < nit; ++it) {
        int ja = s + it * 8 + g * 2;
        int jb = ja + 1;
        int sa = ssrc[min(ja, e - 1)];
        int sb = ssrc[min(jb, e - 1)];
        const float4* Ra = (const float4*)(AH + (size_t)sa * 256 + c8);
        const float4* Rb = (const float4*)(AH + (size_t)sb * 256 + c8);
        float4 aa0 = Ra[0], aa1 = Ra[1];
        float4 ha0 = Ra[32], ha1 = Ra[33];
        float4 ab0 = Rb[0], ab1 = Rb[1];
        float4 hb0 = Rb[32], hb1 = Rb[33];
        float da = fmaxf(aa0.x + b0.x, 0.f) * w0.x + fmaxf(aa0.y + b0.y, 0.f) * w0.y
                 + fmaxf(aa0.z + b0.z, 0.f) * w0.z + fmaxf(aa0.w + b0.w, 0.f) * w0.w
                 + fmaxf(aa1.x + b1.x, 0.f) * w1.x + fmaxf(aa1.y + b1.y, 0.f) * w1.y
                 + fmaxf(aa1.z + b1.z, 0.f) * w1.z + fmaxf(aa1.w + b1.w, 0.f) * w1.w;
        float db = fmaxf(ab0.x + b0.x, 0.f) * w0.x + fmaxf(ab0.y + b0.y, 0.f) * w0.y
                 + fmaxf(ab0.z + b0.z, 0.f) * w0.z + fmaxf(ab0.w + b0.w, 0.f) * w0.w
                 + fmaxf(ab1.x + b1.x, 0.f) * w1.x + fmaxf(ab1.y + b1.y, 0.f) * w1.y
                 + fmaxf(ab1.z + b1.z, 0.f) * w1.z + fmaxf(ab1.w + b1.w, 0.f) * w1.w;
        da += __shfl_xor(da, 1);  db += __shfl_xor(db, 1);
        da += __shfl_xor(da, 2);  db += __shfl_xor(db, 2);
        da += __shfl_xor(da, 4);  db += __shfl_xor(db, 4);
        da += __shfl_xor(da, 8);  db += __shfl_xor(db, 8);
        float wa = (ja < e) ? 1.f / (1.f + expf(-(da + be))) : 0.f;
        float wb = (jb < e) ? 1.f / (1.f + expf(-(db + be))) : 0.f;
        acc0.x += wa * ha0.x + wb * hb0.x; acc0.y += wa * ha0.y + wb * hb0.y;
        acc0.z += wa * ha0.z + wb * hb0.z; acc0.w += wa * ha0.w + wb * hb0.w;
        acc1.x += wa * ha1.x + wb * hb1.x; acc1.y += wa * ha1.y + wb * hb1.y;
        acc1.z += wa * ha1.z + wb * hb1.z; acc1.w += wa * ha1.w + wb * hb1.w;
    }

    #pragma unroll
    for (int o = 16; o <= 32; o <<= 1) {
        acc0.x += __shfl_xor(acc0.x, o); acc0.y += __shfl_xor(acc0.y, o);
        acc0.z += __shfl_xor(acc0.z, o); acc0.w += __shfl_xor(acc0.w, o);
        acc1.x += __shfl_xor(acc1.x, o); acc1.y += __shfl_xor(acc1.y, o);
        acc1.z += __shfl_xor(acc1.z, o); acc1.w += __shfl_xor(acc1.w, o);
    }
    if (g == 0) {
        float4* Op = (float4*)(aggr + (size_t)node * D + c8);
        Op[0] = acc0;
        Op[1] = acc1;
    }
}

// ======================= gate + final LN (64 nodes/block, 16/wave, time-shared tile)
__global__ void __launch_bounds__(256) gate_v7(
    const float* __restrict__ AH, const float* __restrict__ aggr,
    const float* __restrict__ Wg, const float* __restrict__ bg,
    const float* __restrict__ g2, const float* __restrict__ bt2,
    float* __restrict__ out, int N)
{
    __shared__ float ts[NTT][LP];   // h, then aggr (wave-local time-share)
    const int t = threadIdx.x;
    const int q = t >> 6, lane = t & 63;
    const int c = lane;
    const int base = blockIdx.x * NTT;

    // stage h rows (AH[.,128:256])
    {
        int node = t >> 2, c0 = (t & 3) * 32;
        size_t g = (size_t)min(base + node, N - 1) * 256 + 128 + c0;
        const float4* src = (const float4*)(AH + g);
        float4* dst = (float4*)&ts[node][c0];
        #pragma unroll
        for (int i = 0; i < 8; ++i) dst[i] = src[i];
    }

    // save own-col h before overwrite
    float hv[16][2];
    #pragma unroll
    for (int n = 0; n < 16; ++n) {
        hv[n][0] = ts[q*16+n][c];
        hv[n][1] = ts[q*16+n][c + 64];
    }

    // GEMM top: h @ Wg[0:128,:]
    float acc[16][2];
    #pragma unroll
    for (int n = 0; n < 16; ++n) { acc[n][0] = 0.f; acc[n][1] = 0.f; }
    for (int k = 0; k < 128; k += 4) {
        float t00 = Wg[(k+0)*128 + c], t01 = Wg[(k+0)*128 + c + 64];
        float t10 = Wg[(k+1)*128 + c], t11 = Wg[(k+1)*128 + c + 64];
        float t20 = Wg[(k+2)*128 + c], t21 = Wg[(k+2)*128 + c + 64];
        float t30 = Wg[(k+3)*128 + c], t31 = Wg[(k+3)*128 + c + 64];
        #pragma unroll
        for (int n = 0; n < 16; ++n) {
            float4 v = *(const float4*)&ts[q*16+n][k];
            acc[n][0] += v.x*t00 + v.y*t10 + v.z*t20 + v.w*t30;
            acc[n][1] += v.x*t01 + v.y*t11 + v.z*t21 + v.w*t31;
        }
    }

    // overwrite tile with aggr rows (wave-local)
    {
        int node = t >> 2, c0 = (t & 3) * 32;
        size_t g = (size_t)min(base + node, N - 1) * D + c0;
        const float4* src = (const float4*)(aggr + g);
        float4* dst = (float4*)&ts[node][c0];
        #pragma unroll
        for (int i = 0; i < 8; ++i) dst[i] = src[i];
    }

    // GEMM bottom: aggr @ Wg[128:256,:]
    for (int k = 0; k < 128; k += 4) {
        float u00 = Wg[(k+128)*128 + c], u01 = Wg[(k+128)*128 + c + 64];
        float u10 = Wg[(k+129)*128 + c], u11 = Wg[(k+129)*128 + c + 64];
        float u20 = Wg[(k+130)*128 + c], u21 = Wg[(k+130)*128 + c + 64];
        float u30 = Wg[(k+131)*128 + c], u31 = Wg[(k+131)*128 + c + 64];
        #pragma unroll
        for (int n = 0; n < 16; ++n) {
            float4 v = *(const float4*)&ts[q*16+n][k];
            acc[n][0] += v.x*u00 + v.y*u10 + v.z*u20 + v.w*u30;
            acc[n][1] += v.x*u01 + v.y*u11 + v.z*u21 + v.w*u31;
        }
    }

    // gate combine + final LN in registers
    {
        float bg0 = bg[c], bg1 = bg[c + 64];
        float gg0 = g2[c], gg1 = g2[c + 64];
        float bb0 = bt2[c], bb1 = bt2[c + 64];
        #pragma unroll
        for (int n = 0; n < 16; ++n) {
            int node = q*16 + n;
            float av0 = ts[node][c], av1 = ts[node][c + 64];
            float ga = 1.f / (1.f + expf(-(acc[n][0] + bg0)));
            float gb = 1.f / (1.f + expf(-(acc[n][1] + bg1)));
            float y0 = ga * av0 + (1.f - ga) * hv[n][0];
            float y1 = gb * av1 + (1.f - gb) * hv[n][1];
            float s = wave_allsum(y0 + y1);
            float qq = wave_allsum(y0*y0 + y1*y1);
            float m = s * (1.f/128.f);
            float var = qq * (1.f/128.f) - m*m;
            float rs = rsqrtf(var + 1e-5f);
            int gn = base + node;
            if (gn < N) {
                out[(size_t)gn * D + c]      = (y0 - m)*rs*gg0 + bb0;
                out[(size_t)gn * D + c + 64] = (y1 - m)*rs*gg1 + bb1;
            }
        }
    }
}

extern "C" void kernel_launch(void* const* d_in, const int* in_sizes, int n_in,
                              void* d_out, int out_size, void* d_ws, size_t ws_size,
                              hipStream_t stream) {
    const float* x   = (const float*)d_in[0];
    const int*   ei  = (const int*)d_in[1];
    const float* W1  = (const float*)d_in[2];
    const float* b1  = (const float*)d_in[3];
    const float* g1  = (const float*)d_in[4];
    const float* bt1 = (const float*)d_in[5];
    const float* We1 = (const float*)d_in[6];
    const float* be1 = (const float*)d_in[7];
    const float* We2 = (const float*)d_in[8];
    const float* be2 = (const float*)d_in[9];
    const float* Wg  = (const float*)d_in[14];
    const float* bg  = (const float*)d_in[15];
    const float* g2  = (const float*)d_in[16];
    const float* bt2 = (const float*)d_in[17];

    const int N = in_sizes[0] / D;
    const int E = in_sizes[1] / 2;
    const size_t ND = (size_t)N * D;

    float* AH   = (float*)d_ws;          // N x 256 (A | h)
    float* B    = AH + 2 * ND;
    float* aggr = B + ND;
    int* deg    = (int*)(aggr + ND);
    int* off    = deg + (N + 1);
    int* cursor = off + (N + 1);
    int* ssrc   = cursor + (N + 1);
    int* bsum   = ssrc + E;

    (void)hipMemsetAsync(deg, 0, (size_t)(N + 1) * sizeof(int), stream);

    const int nblkT = (N + NTT - 1) / NTT;
    fused_hist_transform<<<HB + nblkT, 256, 0, stream>>>(
        ei, deg, E, x, W1, b1, g1, bt1, We1, be1, AH, B, N);
    scan_a<<<SCB, 256, 0, stream>>>(deg, bsum, N);
    scan_c<<<SCB, 256, 0, stream>>>(deg, bsum, off, cursor, N);
    scatter_kernel<<<(E + 255) / 256, 256, 0, stream>>>(ei, cursor, ssrc, E);
    agg_v6<<<(N + 3) / 4, 256, 0, stream>>>(off, ssrc, AH, B, We2, be2, aggr, N);
    gate_v7<<<nblkT, 256, 0, stream>>>(AH, aggr, Wg, bg, g2, bt2, (float*)d_out, N);
}

// Round 14
// 380.090 us; speedup vs baseline: 1.1802x; 1.1802x over previous
//
#include <hip/hip_runtime.h>
#include <math.h>

#define D 128
#define NT 32
#define LP 132   // padded f32 LDS row
#define SCB 64   // scan blocks
#define HB 256   // histogram blocks fused into transform launch

__device__ __forceinline__ float wave_allsum(float v) {
    #pragma unroll
    for (int off = 32; off; off >>= 1) v += __shfl_xor(v, off);
    return v;
}

// ======================= fused: histogram (blocks 0..HB-1) + transform =======
// transform: h=relu(LN(x@W1+b1)); A=h@We1_top+be1; B=h@We1_bot
// 32 nodes/block, 256 threads, barrier-free, single LDS tile (x then h in place).
// AH[node][0:128]=A, AH[node][128:256]=h
__global__ void __launch_bounds__(256) fused_hist_transform(
    const int* __restrict__ ei, int* __restrict__ deg, int E,
    const float* __restrict__ x, const float* __restrict__ W1, const float* __restrict__ b1,
    const float* __restrict__ g1, const float* __restrict__ bt1,
    const float* __restrict__ We1, const float* __restrict__ be1,
    float* __restrict__ AH, float* __restrict__ B, int N)
{
    if (blockIdx.x < HB) {
        for (int e = blockIdx.x * 256 + threadIdx.x; e < E; e += HB * 256)
            atomicAdd(&deg[ei[E + e]], 1);
        return;
    }
    __shared__ float xs[NT][LP];   // holds x, then h (wave-local reuse)
    const int t = threadIdx.x;
    const int q = t >> 6, lane = t & 63;
    const int c = lane;
    const int base = (blockIdx.x - HB) * NT;

    // stage x: thread t -> node t>>3 (wave q stages exactly its own nodes)
    {
        int node = t >> 3, c0 = (t & 7) * 16;
        int gn = min(base + node, N - 1);
        const float4* src = (const float4*)(x + (size_t)gn * D + c0);
        float4* dst = (float4*)&xs[node][c0];
        dst[0] = src[0]; dst[1] = src[1]; dst[2] = src[2]; dst[3] = src[3];
    }

    // GEMM1: y = x@W1  (native [k][n] weights, coalesced)
    float acc[8][2];
    #pragma unroll
    for (int n = 0; n < 8; ++n) { acc[n][0] = 0.f; acc[n][1] = 0.f; }
    for (int k = 0; k < 128; k += 4) {
        float w00 = W1[(k+0)*128 + c], w01 = W1[(k+0)*128 + c + 64];
        float w10 = W1[(k+1)*128 + c], w11 = W1[(k+1)*128 + c + 64];
        float w20 = W1[(k+2)*128 + c], w21 = W1[(k+2)*128 + c + 64];
        float w30 = W1[(k+3)*128 + c], w31 = W1[(k+3)*128 + c + 64];
        #pragma unroll
        for (int n = 0; n < 8; ++n) {
            float4 xv = *(const float4*)&xs[q*8+n][k];
            acc[n][0] += xv.x*w00 + xv.y*w10 + xv.z*w20 + xv.w*w30;
            acc[n][1] += xv.x*w01 + xv.y*w11 + xv.z*w21 + xv.w*w31;
        }
    }

    // LN + relu in registers; write h back into xs (wave-local, GEMM1 reads done)
    {
        float b0 = b1[c], b1v = b1[c + 64];
        float gg0 = g1[c], gg1 = g1[c + 64];
        float bb0 = bt1[c], bb1 = bt1[c + 64];
        #pragma unroll
        for (int n = 0; n < 8; ++n) {
            int node = q * 8 + n;
            float v0 = acc[n][0] + b0, v1 = acc[n][1] + b1v;
            float s = wave_allsum(v0 + v1);
            float qq = wave_allsum(v0*v0 + v1*v1);
            float m = s * (1.f/128.f);
            float var = qq * (1.f/128.f) - m*m;
            float rs = rsqrtf(var + 1e-5f);
            float h0 = fmaxf((v0 - m)*rs*gg0 + bb0, 0.f);
            float h1 = fmaxf((v1 - m)*rs*gg1 + bb1, 0.f);
            xs[node][c]      = h0;
            xs[node][c + 64] = h1;
            int gn = base + node;
            if (gn < N) {
                AH[(size_t)gn * 256 + 128 + c]      = h0;
                AH[(size_t)gn * 256 + 128 + c + 64] = h1;
            }
        }
    }

    // GEMM2: A = h@We1[0:128,:] + be1 ; B = h@We1[128:256,:]
    float aA[8][2], aB[8][2];
    #pragma unroll
    for (int n = 0; n < 8; ++n) { aA[n][0]=0.f; aA[n][1]=0.f; aB[n][0]=0.f; aB[n][1]=0.f; }
    for (int k = 0; k < 128; k += 4) {
        float t00 = We1[(k+0)*128 + c],   t01 = We1[(k+0)*128 + c + 64];
        float t10 = We1[(k+1)*128 + c],   t11 = We1[(k+1)*128 + c + 64];
        float t20 = We1[(k+2)*128 + c],   t21 = We1[(k+2)*128 + c + 64];
        float t30 = We1[(k+3)*128 + c],   t31 = We1[(k+3)*128 + c + 64];
        float u00 = We1[(k+128)*128 + c], u01 = We1[(k+128)*128 + c + 64];
        float u10 = We1[(k+129)*128 + c], u11 = We1[(k+129)*128 + c + 64];
        float u20 = We1[(k+130)*128 + c], u21 = We1[(k+130)*128 + c + 64];
        float u30 = We1[(k+131)*128 + c], u31 = We1[(k+131)*128 + c + 64];
        #pragma unroll
        for (int n = 0; n < 8; ++n) {
            float4 hv = *(const float4*)&xs[q*8+n][k];
            aA[n][0] += hv.x*t00 + hv.y*t10 + hv.z*t20 + hv.w*t30;
            aA[n][1] += hv.x*t01 + hv.y*t11 + hv.z*t21 + hv.w*t31;
            aB[n][0] += hv.x*u00 + hv.y*u10 + hv.z*u20 + hv.w*u30;
            aB[n][1] += hv.x*u01 + hv.y*u11 + hv.z*u21 + hv.w*u31;
        }
    }
    {
        float be0 = be1[c], be1v = be1[c + 64];
        #pragma unroll
        for (int n = 0; n < 8; ++n) {
            int gn = base + q*8 + n;
            if (gn < N) {
                AH[(size_t)gn * 256 + c]      = aA[n][0] + be0;
                AH[(size_t)gn * 256 + c + 64] = aA[n][1] + be1v;
                B[(size_t)gn * D + c]         = aB[n][0];
                B[(size_t)gn * D + c + 64]    = aB[n][1];
            }
        }
    }
}

// ---- CSR build ----
__global__ void __launch_bounds__(256) scan_a(const int* __restrict__ deg,
                                              int* __restrict__ bsum, int N) {
    __shared__ int red[256];
    const int b = blockIdx.x, t = threadIdx.x;
    const int C = (N + SCB - 1) / SCB;
    const int W = (C + 255) / 256;
    int s0 = b * C + t * W;
    int s1 = min(s0 + W, min((b + 1) * C, N));
    int s = 0;
    for (int i = s0; i < s1; ++i) s += deg[i];
    red[t] = s;
    __syncthreads();
    #pragma unroll
    for (int d = 128; d; d >>= 1) {
        if (t < d) red[t] += red[t + d];
        __syncthreads();
    }
    if (t == 0) bsum[b] = red[0];
}

__global__ void __launch_bounds__(256) scan_c(const int* __restrict__ deg,
                                              const int* __restrict__ bsum,
                                              int* __restrict__ off,
                                              int* __restrict__ cursor, int N) {
    __shared__ int pre[256];
    __shared__ int bofs;
    const int b = blockIdx.x, t = threadIdx.x;
    const int C = (N + SCB - 1) / SCB;
    const int W = (C + 255) / 256;
    if (t == 0) {
        int r = 0;
        for (int i = 0; i < b; ++i) r += bsum[i];
        bofs = r;
        if (b == SCB - 1) off[N] = r + bsum[b];
    }
    int s0 = b * C + t * W;
    int s1 = min(s0 + W, min((b + 1) * C, N));
    int s = 0;
    for (int i = s0; i < s1; ++i) s += deg[i];
    pre[t] = s;
    __syncthreads();
    for (int d = 1; d < 256; d <<= 1) {
        int vv = (t >= d) ? pre[t - d] : 0;
        __syncthreads();
        if (t >= d) pre[t] += vv;
        __syncthreads();
    }
    int run = bofs + ((t == 0) ? 0 : pre[t - 1]);
    for (int i = s0; i < s1; ++i) {
        off[i] = run;
        cursor[i] = run;
        run += deg[i];
    }
}

__global__ void __launch_bounds__(256) scatter_kernel(const int* __restrict__ ei,
                                                      int* __restrict__ cursor,
                                                      int* __restrict__ ssrc, int E) {
    int e = blockIdx.x * 256 + threadIdx.x;
    if (e < E) {
        int pos = atomicAdd(&cursor[ei[E + e]], 1);
        ssrc[pos] = ei[e];
    }
}

// ======================= pull aggregation: wave/node, 16 lanes/edge, 8 edges in flight
// ssrc segment preloaded via one coalesced wave read; per-edge index via __shfl.
__global__ void __launch_bounds__(256) agg_v7(
    const int* __restrict__ off, const int* __restrict__ ssrc,
    const float* __restrict__ AH, const float* __restrict__ B,
    const float* __restrict__ We2, const float* __restrict__ be2,
    float* __restrict__ aggr, int N)
{
    const int wid = threadIdx.x >> 6, lane = threadIdx.x & 63;
    const int node = blockIdx.x * 4 + wid;
    if (node >= N) return;
    const int g = lane >> 4;
    const int c8 = (lane & 15) * 8;

    const int s = off[node], e = off[node + 1];
    const int deg = e - s;

    if (deg <= 0) {
        if (g == 0) {
            float4 z = make_float4(0.f,0.f,0.f,0.f);
            float4* Op = (float4*)(aggr + (size_t)node * D + c8);
            Op[0] = z; Op[1] = z;
        }
        return;
    }

    const float4* Bp = (const float4*)(B + (size_t)node * D + c8);
    float4 b0 = Bp[0], b1 = Bp[1];
    const float4* Wp = (const float4*)(We2 + c8);
    float4 w0 = Wp[0], w1 = Wp[1];
    const float be = be2[0];

    float4 acc0 = make_float4(0.f,0.f,0.f,0.f);
    float4 acc1 = make_float4(0.f,0.f,0.f,0.f);

    if (deg <= 64) {
        // one coalesced wave read of the whole segment
        int myidx = ssrc[min(s + lane, e - 1)];
        const int nit = (deg + 7) >> 3;
        for (int it = 0; it < nit; ++it) {
            int ja = it * 8 + g * 2;
            int jb = ja + 1;
            int sa = __shfl(myidx, min(ja, deg - 1));
            int sb = __shfl(myidx, min(jb, deg - 1));
            const float4* Ra = (const float4*)(AH + (size_t)sa * 256 + c8);
            const float4* Rb = (const float4*)(AH + (size_t)sb * 256 + c8);
            float4 aa0 = Ra[0], aa1 = Ra[1];
            float4 ha0 = Ra[32], ha1 = Ra[33];
            float4 ab0 = Rb[0], ab1 = Rb[1];
            float4 hb0 = Rb[32], hb1 = Rb[33];
            float da = fmaxf(aa0.x + b0.x, 0.f) * w0.x + fmaxf(aa0.y + b0.y, 0.f) * w0.y
                     + fmaxf(aa0.z + b0.z, 0.f) * w0.z + fmaxf(aa0.w + b0.w, 0.f) * w0.w
                     + fmaxf(aa1.x + b1.x, 0.f) * w1.x + fmaxf(aa1.y + b1.y, 0.f) * w1.y
                     + fmaxf(aa1.z + b1.z, 0.f) * w1.z + fmaxf(aa1.w + b1.w, 0.f) * w1.w;
            float db = fmaxf(ab0.x + b0.x, 0.f) * w0.x + fmaxf(ab0.y + b0.y, 0.f) * w0.y
                     + fmaxf(ab0.z + b0.z, 0.f) * w0.z + fmaxf(ab0.w + b0.w, 0.f) * w0.w
                     + fmaxf(ab1.x + b1.x, 0.f) * w1.x + fmaxf(ab1.y + b1.y, 0.f) * w1.y
                     + fmaxf(ab1.z + b1.z, 0.f) * w1.z + fmaxf(ab1.w + b1.w, 0.f) * w1.w;
            da += __shfl_xor(da, 1);  db += __shfl_xor(db, 1);
            da += __shfl_xor(da, 2);  db += __shfl_xor(db, 2);
            da += __shfl_xor(da, 4);  db += __shfl_xor(db, 4);
            da += __shfl_xor(da, 8);  db += __shfl_xor(db, 8);
            float wa = (ja < deg) ? 1.f / (1.f + expf(-(da + be))) : 0.f;
            float wb = (jb < deg) ? 1.f / (1.f + expf(-(db + be))) : 0.f;
            acc0.x += wa * ha0.x + wb * hb0.x; acc0.y += wa * ha0.y + wb * hb0.y;
            acc0.z += wa * ha0.z + wb * hb0.z; acc0.w += wa * ha0.w + wb * hb0.w;
            acc1.x += wa * ha1.x + wb * hb1.x; acc1.y += wa * ha1.y + wb * hb1.y;
            acc1.z += wa * ha1.z + wb * hb1.z; acc1.w += wa * ha1.w + wb * hb1.w;
        }
    } else {
        const int nit = (deg + 7) >> 3;
        for (int it = 0; it < nit; ++it) {
            int ja = s + it * 8 + g * 2;
            int jb = ja + 1;
            int sa = ssrc[min(ja, e - 1)];
            int sb = ssrc[min(jb, e - 1)];
            const float4* Ra = (const float4*)(AH + (size_t)sa * 256 + c8);
            const float4* Rb = (const float4*)(AH + (size_t)sb * 256 + c8);
            float4 aa0 = Ra[0], aa1 = Ra[1];
            float4 ha0 = Ra[32], ha1 = Ra[33];
            float4 ab0 = Rb[0], ab1 = Rb[1];
            float4 hb0 = Rb[32], hb1 = Rb[33];
            float da = fmaxf(aa0.x + b0.x, 0.f) * w0.x + fmaxf(aa0.y + b0.y, 0.f) * w0.y
                     + fmaxf(aa0.z + b0.z, 0.f) * w0.z + fmaxf(aa0.w + b0.w, 0.f) * w0.w
                     + fmaxf(aa1.x + b1.x, 0.f) * w1.x + fmaxf(aa1.y + b1.y, 0.f) * w1.y
                     + fmaxf(aa1.z + b1.z, 0.f) * w1.z + fmaxf(aa1.w + b1.w, 0.f) * w1.w;
            float db = fmaxf(ab0.x + b0.x, 0.f) * w0.x + fmaxf(ab0.y + b0.y, 0.f) * w0.y
                     + fmaxf(ab0.z + b0.z, 0.f) * w0.z + fmaxf(ab0.w + b0.w, 0.f) * w0.w
                     + fmaxf(ab1.x + b1.x, 0.f) * w1.x + fmaxf(ab1.y + b1.y, 0.f) * w1.y
                     + fmaxf(ab1.z + b1.z, 0.f) * w1.z + fmaxf(ab1.w + b1.w, 0.f) * w1.w;
            da += __shfl_xor(da, 1);  db += __shfl_xor(db, 1);
            da += __shfl_xor(da, 2);  db += __shfl_xor(db, 2);
            da += __shfl_xor(da, 4);  db += __shfl_xor(db, 4);
            da += __shfl_xor(da, 8);  db += __shfl_xor(db, 8);
            float wa = (ja < e) ? 1.f / (1.f + expf(-(da + be))) : 0.f;
            float wb = (jb < e) ? 1.f / (1.f + expf(-(db + be))) : 0.f;
            acc0.x += wa * ha0.x + wb * hb0.x; acc0.y += wa * ha0.y + wb * hb0.y;
            acc0.z += wa * ha0.z + wb * hb0.z; acc0.w += wa * ha0.w + wb * hb0.w;
            acc1.x += wa * ha1.x + wb * hb1.x; acc1.y += wa * ha1.y + wb * hb1.y;
            acc1.z += wa * ha1.z + wb * hb1.z; acc1.w += wa * ha1.w + wb * hb1.w;
        }
    }

    #pragma unroll
    for (int o = 16; o <= 32; o <<= 1) {
        acc0.x += __shfl_xor(acc0.x, o); acc0.y += __shfl_xor(acc0.y, o);
        acc0.z += __shfl_xor(acc0.z, o); acc0.w += __shfl_xor(acc0.w, o);
        acc1.x += __shfl_xor(acc1.x, o); acc1.y += __shfl_xor(acc1.y, o);
        acc1.z += __shfl_xor(acc1.z, o); acc1.w += __shfl_xor(acc1.w, o);
    }
    if (g == 0) {
        float4* Op = (float4*)(aggr + (size_t)node * D + c8);
        Op[0] = acc0;
        Op[1] = acc1;
    }
}

// ======================= gate + final LN (32 nodes/block, barrier-free, single tile)
__global__ void __launch_bounds__(256) gate_v6(
    const float* __restrict__ AH, const float* __restrict__ aggr,
    const float* __restrict__ Wg, const float* __restrict__ bg,
    const float* __restrict__ g2, const float* __restrict__ bt2,
    float* __restrict__ out, int N)
{
    __shared__ float ts[NT][LP];   // holds h, then aggr (wave-local time-share)
    const int t = threadIdx.x;
    const int q = t >> 6, lane = t & 63;
    const int c = lane;
    const int base = blockIdx.x * NT;

    // stage h rows (from AH[.,128:256])
    {
        int node = t >> 3, c0 = (t & 7) * 16;
        size_t g = (size_t)min(base + node, N - 1) * 256 + 128 + c0;
        const float4* src = (const float4*)(AH + g);
        float4* dst = (float4*)&ts[node][c0];
        dst[0] = src[0]; dst[1] = src[1]; dst[2] = src[2]; dst[3] = src[3];
    }

    // save own-col h values before tile is overwritten
    float hv[8][2];
    #pragma unroll
    for (int n = 0; n < 8; ++n) {
        hv[n][0] = ts[q*8+n][c];
        hv[n][1] = ts[q*8+n][c + 64];
    }

    // GEMM top half: h @ Wg[0:128,:]
    float acc[8][2];
    #pragma unroll
    for (int n = 0; n < 8; ++n) { acc[n][0] = 0.f; acc[n][1] = 0.f; }
    for (int k = 0; k < 128; k += 4) {
        float t00 = Wg[(k+0)*128 + c], t01 = Wg[(k+0)*128 + c + 64];
        float t10 = Wg[(k+1)*128 + c], t11 = Wg[(k+1)*128 + c + 64];
        float t20 = Wg[(k+2)*128 + c], t21 = Wg[(k+2)*128 + c + 64];
        float t30 = Wg[(k+3)*128 + c], t31 = Wg[(k+3)*128 + c + 64];
        #pragma unroll
        for (int n = 0; n < 8; ++n) {
            float4 v = *(const float4*)&ts[q*8+n][k];
            acc[n][0] += v.x*t00 + v.y*t10 + v.z*t20 + v.w*t30;
            acc[n][1] += v.x*t01 + v.y*t11 + v.z*t21 + v.w*t31;
        }
    }

    // overwrite tile with aggr rows (wave-local; GEMM-top reads complete)
    {
        int node = t >> 3, c0 = (t & 7) * 16;
        size_t g = (size_t)min(base + node, N - 1) * D + c0;
        const float4* src = (const float4*)(aggr + g);
        float4* dst = (float4*)&ts[node][c0];
        dst[0] = src[0]; dst[1] = src[1]; dst[2] = src[2]; dst[3] = src[3];
    }

    // GEMM bottom half: aggr @ Wg[128:256,:]
    for (int k = 0; k < 128; k += 4) {
        float u00 = Wg[(k+128)*128 + c], u01 = Wg[(k+128)*128 + c + 64];
        float u10 = Wg[(k+129)*128 + c], u11 = Wg[(k+129)*128 + c + 64];
        float u20 = Wg[(k+130)*128 + c], u21 = Wg[(k+130)*128 + c + 64];
        float u30 = Wg[(k+131)*128 + c], u31 = Wg[(k+131)*128 + c + 64];
        #pragma unroll
        for (int n = 0; n < 8; ++n) {
            float4 v = *(const float4*)&ts[q*8+n][k];
            acc[n][0] += v.x*u00 + v.y*u10 + v.z*u20 + v.w*u30;
            acc[n][1] += v.x*u01 + v.y*u11 + v.z*u21 + v.w*u31;
        }
    }

    // gate combine (aggr still in tile) + final LN in registers
    {
        float bg0 = bg[c], bg1 = bg[c + 64];
        float gg0 = g2[c], gg1 = g2[c + 64];
        float bb0 = bt2[c], bb1 = bt2[c + 64];
        #pragma unroll
        for (int n = 0; n < 8; ++n) {
            int node = q*8 + n;
            float av0 = ts[node][c], av1 = ts[node][c + 64];
            float ga = 1.f / (1.f + expf(-(acc[n][0] + bg0)));
            float gb = 1.f / (1.f + expf(-(acc[n][1] + bg1)));
            float y0 = ga * av0 + (1.f - ga) * hv[n][0];
            float y1 = gb * av1 + (1.f - gb) * hv[n][1];
            float s = wave_allsum(y0 + y1);
            float qq = wave_allsum(y0*y0 + y1*y1);
            float m = s * (1.f/128.f);
            float var = qq * (1.f/128.f) - m*m;
            float rs = rsqrtf(var + 1e-5f);
            int gn = base + node;
            if (gn < N) {
                out[(size_t)gn * D + c]      = (y0 - m)*rs*gg0 + bb0;
                out[(size_t)gn * D + c + 64] = (y1 - m)*rs*gg1 + bb1;
            }
        }
    }
}

extern "C" void kernel_launch(void* const* d_in, const int* in_sizes, int n_in,
                              void* d_out, int out_size, void* d_ws, size_t ws_size,
                              hipStream_t stream) {
    const float* x   = (const float*)d_in[0];
    const int*   ei  = (const int*)d_in[1];
    const float* W1  = (const float*)d_in[2];
    const float* b1  = (const float*)d_in[3];
    const float* g1  = (const float*)d_in[4];
    const float* bt1 = (const float*)d_in[5];
    const float* We1 = (const float*)d_in[6];
    const float* be1 = (const float*)d_in[7];
    const float* We2 = (const float*)d_in[8];
    const float* be2 = (const float*)d_in[9];
    const float* Wg  = (const float*)d_in[14];
    const float* bg  = (const float*)d_in[15];
    const float* g2  = (const float*)d_in[16];
    const float* bt2 = (const float*)d_in[17];

    const int N = in_sizes[0] / D;
    const int E = in_sizes[1] / 2;
    const size_t ND = (size_t)N * D;

    float* AH   = (float*)d_ws;          // N x 256 (A | h)
    float* B    = AH + 2 * ND;
    float* aggr = B + ND;
    int* deg    = (int*)(aggr + ND);
    int* off    = deg + (N + 1);
    int* cursor = off + (N + 1);
    int* ssrc   = cursor + (N + 1);
    int* bsum   = ssrc + E;

    (void)hipMemsetAsync(deg, 0, (size_t)(N + 1) * sizeof(int), stream);

    const int nblkT = (N + NT - 1) / NT;
    fused_hist_transform<<<HB + nblkT, 256, 0, stream>>>(
        ei, deg, E, x, W1, b1, g1, bt1, We1, be1, AH, B, N);
    scan_a<<<SCB, 256, 0, stream>>>(deg, bsum, N);
    scan_c<<<SCB, 256, 0, stream>>>(deg, bsum, off, cursor, N);
    scatter_kernel<<<(E + 255) / 256, 256, 0, stream>>>(ei, cursor, ssrc, E);
    agg_v7<<<(N + 3) / 4, 256, 0, stream>>>(off, ssrc, AH, B, We2, be2, aggr, N);
    gate_v6<<<nblkT, 256, 0, stream>>>(AH, aggr, Wg, bg, g2, bt2, (float*)d_out, N);
}